// Round 14
// baseline (338.153 us; speedup 1.0000x reference)
//
#include <hip/hip_runtime.h>
#include <hip/hip_bf16.h>

typedef unsigned short u16;
typedef __attribute__((ext_vector_type(8))) short short8;
typedef __attribute__((ext_vector_type(4))) short short4v;
typedef __attribute__((ext_vector_type(4))) float f32x4;

#define NEGV -1000000000000000.0f
#define SBAR() asm volatile("s_barrier" ::: "memory")

__device__ __forceinline__ u16 f2bf(float f) {
  unsigned u = __float_as_uint(f);
  unsigned r = (u + 0x7FFFu + ((u >> 16) & 1u)) >> 16;
  return (u16)r;
}
__device__ __forceinline__ float bf2f(u16 s) {
  return __uint_as_float(((unsigned)s) << 16);
}
__device__ __forceinline__ void lds16(const void* g, void* l) {
  __builtin_amdgcn_global_load_lds((const __attribute__((address_space(1))) void*)g,
                                   (__attribute__((address_space(3))) void*)l,
                                   16, 0, 0);
}

// ============ 256x256 GEMM, 16 waves (4Mx4N, 64x64/wave): out = Wrb @ O^T ===
// r8 schedule, barrier-trimmed (r14): 2 s_barrier per K-tile instead of 4.
// Hazard proof: SBAR#1 (post-vmcnt) publishes A(t+1)/B(t+1) complete;
// SBAR#2 (end of tile) fences p0-stage-over-Ac(t-1) (slow waves' p1 reads
// lgkm-complete before their MFMA, hence before SBAR#2). p0 needs no barrier:
// stage targets An (unread until after next SBAR#1), reads target current bufs.
__global__ __launch_bounds__(1024) void gemm8b(const u16* __restrict__ A,
                                               const u16* __restrict__ B,
                                               float* __restrict__ out) {
  extern __shared__ u16 lds[];
  const int bid = blockIdx.x;
  const int wg = (bid & 7) * 64 + (bid >> 3);  // m-pair shares B-tile on one XCD
  const int m0 = (wg & 1) * 256;
  const int n0 = (wg >> 1) * 256;
  const int tid = threadIdx.x;
  const int lane = tid & 63;
  const int w = tid >> 6;   // 0..15
  const int wr = w >> 2;    // 64-row band
  const int wc = w & 3;     // 64-col band
  const int fro = lane & 15;
  const int hi = lane >> 4;
  const int kx = fro & 7;
  const int sr = lane >> 3;
  const int sgc = ((lane & 7) ^ sr) << 3;  // pre-swizzled source col (elems)

  const u16* Ag = A + (size_t)m0 * 2048;
  const u16* Bg = B + (size_t)n0 * 2048;
  const int rA = wr * 64 + fro;
  const int rB = wc * 64 + fro;

  f32x4 acc[4][4] = {};

#define STG(gp, lp) \
  lds16((gp) + (size_t)(w * 8 + sr) * 2048 + sgc, (u16*)(lp) + w * 512)
#define RDF(base, row, k16) \
  (*(const short8*)&(base)[(size_t)(row) * 64 + (((k16) ^ kx) << 3)])

  // prologue: A0, B0, B1
  STG(Ag, lds);
  STG(Ag + 262144, lds + 8192);
  STG(Bg, lds + 32768);
  STG(Bg + 262144, lds + 32768 + 8192);
  STG(Bg + 64, lds + 49152);
  STG(Bg + 262144 + 64, lds + 57344);
  asm volatile("s_waitcnt vmcnt(2)" ::: "memory");  // A0,B0 done; B1 in flight
  SBAR();

  const u16* Ac = lds;
  u16* An = lds + 16384;
  const u16* Bc = lds + 32768;   // B(t)
  const u16* Bn = lds + 49152;   // B(t+1)
  u16* Bs2 = lds + 65536;        // stage target B(t+2)

  for (int t = 0; t < 32; ++t) {
    const int kkA = (t < 31 ? t + 1 : 31) * 64;
    const int kkB = (t < 30 ? t + 2 : 31) * 64;
    short8 af[4], bf[4];

    // ---- phase 0 (ks=0): 8 ds_read; stage A(t+1); 16 MFMA  (no barrier)
#pragma unroll
    for (int i = 0; i < 4; ++i) af[i] = RDF(Ac, rA + i * 16, hi);
#pragma unroll
    for (int j = 0; j < 4; ++j) bf[j] = RDF(Bc, rB + j * 16, hi);
    STG(Ag + kkA, An);
    STG(Ag + 262144 + kkA, An + 8192);
    __builtin_amdgcn_s_setprio(1);
#pragma unroll
    for (int i = 0; i < 4; ++i)
#pragma unroll
      for (int j = 0; j < 4; ++j)
        acc[i][j] =
            __builtin_amdgcn_mfma_f32_16x16x32_bf16(af[i], bf[j], acc[i][j], 0, 0, 0);
    __builtin_amdgcn_s_setprio(0);

    // ---- phase 1 (ks=1): 8 ds_read; stage B(t+2); vmcnt(2); SBAR; 16 MFMA; SBAR
#pragma unroll
    for (int i = 0; i < 4; ++i) af[i] = RDF(Ac, rA + i * 16, 4 + hi);
#pragma unroll
    for (int j = 0; j < 4; ++j) bf[j] = RDF(Bc, rB + j * 16, 4 + hi);
    STG(Bg + kkB, Bs2);
    STG(Bg + 262144 + kkB, Bs2 + 8192);
    asm volatile("s_waitcnt vmcnt(2)" ::: "memory");  // drain B(t+1), A(t+1)
    SBAR();
    __builtin_amdgcn_s_setprio(1);
#pragma unroll
    for (int i = 0; i < 4; ++i)
#pragma unroll
      for (int j = 0; j < 4; ++j)
        acc[i][j] =
            __builtin_amdgcn_mfma_f32_16x16x32_bf16(af[i], bf[j], acc[i][j], 0, 0, 0);
    __builtin_amdgcn_s_setprio(0);
    SBAR();

    // rotate buffers
    u16* tA = An; An = (u16*)Ac; Ac = tA;
    u16* tB = (u16*)Bc; Bc = Bn; Bn = Bs2; Bs2 = tB;
  }
  asm volatile("s_waitcnt vmcnt(0)" ::: "memory");

  // ---- epilogue: out[b][r][c], n = n0 + wc*64 + j*16 + fro
  const int crow = m0 + wr * 64 + hi * 4;
#pragma unroll
  for (int i = 0; i < 4; ++i)
#pragma unroll
    for (int j = 0; j < 4; ++j) {
      const int n = n0 + wc * 64 + j * 16 + fro;
      float* op = out + (size_t)(n >> 10) * 524288 + (n & 1023);
#pragma unroll
      for (int g = 0; g < 4; ++g)
        op[(size_t)(crow + i * 16 + g) * 1024] = acc[i][j][g];
    }
#undef STG
#undef RDF
}

// ============ S-GEMM + fused dual softmax + transposed-Eun epilogue =========
// dbuf counted-vmcnt staging; XCD-swizzled grid.
__global__ __launch_bounds__(256) void gemm_s(
    const u16* __restrict__ A, const u16* __restrict__ Bq,
    const float* __restrict__ cb, const float* __restrict__ qb,
    const float* __restrict__ cmask, const float* __restrict__ qmask,
    u16* __restrict__ Sbar, u16* __restrict__ EunT, float* __restrict__ csum) {
  __shared__ u16 As[2][128 * 64];
  __shared__ u16 Bs[2][128 * 64];
  __shared__ u16 Lt[128][136];
  __shared__ float rmaxs[2][128];
  __shared__ float rsums[2][128];
  __shared__ float cparts[2][128];
  const int bid = blockIdx.x;
  const int xcd = bid & 7;
  const int kk = bid >> 3;            // 0..63
  const int b = xcd * 8 + (kk >> 3);  // 8 m-tiles of one b share an XCD
  const int m0 = (kk & 7) * 128;
  const u16* Ab = A + (size_t)b * 2097152;
  const u16* Bb = Bq + (size_t)b * 65536;
  const int t = threadIdx.x;
  const int lane = t & 63;
  const int w = t >> 6;
  const int wr = w >> 1, wc = w & 1;
  const int srow = lane >> 3;
  const int scol = (lane & 7) * 8;

  f32x4 acc[4][4] = {};

#define SSTG(k0, sel)                                                         \
  {                                                                           \
    _Pragma("unroll") for (int qq = 0; qq < 4; ++qq) {                        \
      const int q = w * 4 + qq;                                               \
      const int r = q * 8 + srow;                                             \
      lds16(Ab + (size_t)(m0 + r) * 2048 + (k0) + scol, &As[sel][q * 512]);   \
      lds16(Bb + (size_t)r * 512 + (k0) + scol, &Bs[sel][q * 512]);           \
    }                                                                         \
  }

  SSTG(0, 0);
  for (int it = 0; it < 8; ++it) {
    if (it < 7) {
      SSTG((it + 1) * 64, (it + 1) & 1);
      asm volatile("s_waitcnt vmcnt(8)" ::: "memory");  // drain tile it only
    } else {
      asm volatile("s_waitcnt vmcnt(0)" ::: "memory");
    }
    SBAR();
    const u16* Asc = As[it & 1];
    const u16* Bsc = Bs[it & 1];
#pragma unroll
    for (int ks = 0; ks < 2; ++ks) {
      short8 af[4], bg[4];
      const int fro = lane & 15;
      const int k8 = ks * 32 + (lane >> 4) * 8;
#pragma unroll
      for (int i = 0; i < 4; ++i)
        af[i] = *(const short8*)&Asc[(wr * 64 + i * 16 + fro) * 64 + k8];
#pragma unroll
      for (int i = 0; i < 4; ++i)
        bg[i] = *(const short8*)&Bsc[(wc * 64 + i * 16 + fro) * 64 + k8];
#pragma unroll
      for (int i = 0; i < 4; ++i)
#pragma unroll
        for (int j = 0; j < 4; ++j)
          acc[i][j] =
              __builtin_amdgcn_mfma_f32_16x16x32_bf16(af[i], bg[j], acc[i][j], 0, 0, 0);
    }
    SBAR();
  }
#undef SSTG

  const int fro = lane & 15;
  const int hi = lane >> 4;
  float qv[4], qbv[4];
#pragma unroll
  for (int j = 0; j < 4; ++j) {
    const int cc = wc * 64 + j * 16 + fro;
    qv[j] = qmask[b * 128 + cc];
    qbv[j] = qb[b * 128 + cc];
  }
  float colp[4] = {0.f, 0.f, 0.f, 0.f};
#pragma unroll
  for (int i = 0; i < 4; ++i)
#pragma unroll
    for (int g = 0; g < 4; ++g) {
      const int rl = wr * 64 + i * 16 + hi * 4 + g;
      const float rb = cb[b * 1024 + m0 + rl];
      const float cv = cmask[b * 1024 + m0 + rl];
      const float coff = NEGV * (1.f - cv);
#pragma unroll
      for (int j = 0; j < 4; ++j) {
        const float v = acc[i][j][g] + rb + qbv[j];
        acc[i][j][g] = v;
        const float e = __expf(v * cv + coff);
        Lt[wc * 64 + j * 16 + fro][rl] = f2bf(e);
        colp[j] += e;
      }
    }
#pragma unroll
  for (int j = 0; j < 4; ++j) {
    colp[j] += __shfl_xor(colp[j], 16);
    colp[j] += __shfl_xor(colp[j], 32);
  }
  if (hi == 0)
#pragma unroll
    for (int j = 0; j < 4; ++j) cparts[wr][wc * 64 + j * 16 + fro] = colp[j];
  float rtmp[4][4];
#pragma unroll
  for (int i = 0; i < 4; ++i)
#pragma unroll
    for (int g = 0; g < 4; ++g) {
      float m = -3.4e38f;
#pragma unroll
      for (int j = 0; j < 4; ++j) {
        const float xm = acc[i][j][g] * qv[j] + NEGV * (1.f - qv[j]);
        acc[i][j][g] = xm;
        m = fmaxf(m, xm);
      }
#pragma unroll
      for (int o = 8; o; o >>= 1) m = fmaxf(m, __shfl_xor(m, o));
      rtmp[i][g] = m;
    }
  if (fro == 0)
#pragma unroll
    for (int i = 0; i < 4; ++i)
#pragma unroll
      for (int g = 0; g < 4; ++g)
        rmaxs[wc][wr * 64 + i * 16 + hi * 4 + g] = rtmp[i][g];
  __syncthreads();
  if (t < 128) atomicAdd(&csum[b * 128 + t], cparts[0][t] + cparts[1][t]);
  {
    const int jr = t >> 1;
    const int ih = (t & 1) * 64;
    u16* dst = EunT + (size_t)b * 131072 + (size_t)jr * 1024 + m0 + ih;
#pragma unroll
    for (int s = 0; s < 8; ++s)
      *(short8*)(dst + s * 8) = *(const short8*)&Lt[jr][ih + s * 8];
  }
#pragma unroll
  for (int i = 0; i < 4; ++i)
#pragma unroll
    for (int g = 0; g < 4; ++g) {
      const int rl = wr * 64 + i * 16 + hi * 4 + g;
      const float M = fmaxf(rmaxs[0][rl], rmaxs[1][rl]);
      float s = 0.f;
#pragma unroll
      for (int j = 0; j < 4; ++j) {
        const float p = __expf(acc[i][j][g] - M);
        acc[i][j][g] = p;
        s += p;
      }
#pragma unroll
      for (int o = 8; o; o >>= 1) s += __shfl_xor(s, o);
      rtmp[i][g] = s;
    }
  if (fro == 0)
#pragma unroll
    for (int i = 0; i < 4; ++i)
#pragma unroll
      for (int g = 0; g < 4; ++g)
        rsums[wc][wr * 64 + i * 16 + hi * 4 + g] = rtmp[i][g];
  __syncthreads();
#pragma unroll
  for (int i = 0; i < 4; ++i)
#pragma unroll
    for (int g = 0; g < 4; ++g) {
      const int rl = wr * 64 + i * 16 + hi * 4 + g;
      const float inv = 1.f / (rsums[0][rl] + rsums[1][rl]);
#pragma unroll
      for (int j = 0; j < 4; ++j)
        Sbar[((size_t)b * 1024 + m0 + rl) * 128 + wc * 64 + j * 16 + fro] =
            f2bf(acc[i][j][g] * inv);
    }
}

// ============ merged T-GEMM + A/Bm GEMM: XCD-swizzled grid, 512 thr, 160KB ==
__global__ __launch_bounds__(512) void gemm_tab(
    const u16* __restrict__ EunT, const u16* __restrict__ Corig,
    const float* __restrict__ csum, const u16* __restrict__ Sbar,
    const u16* __restrict__ Qo, u16* __restrict__ O) {
  extern __shared__ u16 sh[];
  u16* LQ = sh;             // 32KB Qo tile
  u16* LT = sh + 16384;     // 32KB T tile
  u16* Ls = sh + 65536;     // 32KB epilogue scratch
  const int bid = blockIdx.x;
  const int xcd = bid & 7;
  const int kb = bid >> 3;            // 0..31
  const int b = xcd * 8 + (kb >> 2);  // 4 dcol-blocks of one b share an XCD
  const int dcol = (kb & 3) * 128;
  const int t = threadIdx.x;
  const int lane = t & 63;
  const int w = t >> 6;
  const int wr = w >> 2, wc = w & 3;
  const int fro = lane & 15, hi = lane >> 4;
  const int srow4 = t >> 4;   // 0..31
  const int sslot = t & 15;   // 16B slot

#define STG32(gp, lp)                                                         \
  {                                                                           \
    _Pragma("unroll") for (int ii = 0; ii < 4; ++ii) {                        \
      const int row_ = ii * 32 + srow4;                                       \
      lds16((gp) + (size_t)row_ * 128 + ((sslot ^ (row_ & 7)) << 3),          \
            (u16*)(lp) + ii * 4096 + t * 8);                                  \
    }                                                                         \
  }
#define RDS(base, row, kslot)                                                 \
  (*(const short8*)&(base)[(size_t)(row) * 128 + (((kslot) ^ ((row) & 7)) << 3)])
// stage a 128x64 bf16 K-tile (linear layout [row][64]), 2 gloads/thread
#define TSTG(gp, lp)                                                          \
  {                                                                           \
    _Pragma("unroll") for (int q = 0; q < 2; ++q) {                           \
      const int row_ = q * 64 + (t >> 3);                                     \
      lds16((gp) + (size_t)row_ * 1024 + ((t & 7) << 3),                      \
            (u16*)(lp) + q * 4096 + t * 8);                                   \
    }                                                                         \
  }

  // ---- issue LQ stage early; drains at phase T's first counted vmcnt
  STG32(Qo + (size_t)b * 65536 + (size_t)dcol * 128, LQ);

  // ================= phase T (double-buffered staging) =================
  {
    const u16* Ag = EunT + (size_t)b * 131072;                       // [128j][1024i]
    const u16* Bg = Corig + (size_t)b * 524288 + (size_t)dcol * 1024;// [128d][1024i]
    f32x4 acc[4][2] = {};
    TSTG(Ag, sh + 32768);          // TA0
    TSTG(Bg, sh + 40960);          // TB0
    for (int k = 0; k < 16; ++k) {
      if (k < 15) {
        u16* nb = sh + 32768 + ((k + 1) & 1) * 16384;
        TSTG(Ag + (k + 1) * 64, nb);
        TSTG(Bg + (k + 1) * 64, nb + 8192);
        asm volatile("s_waitcnt vmcnt(4)" ::: "memory");  // drain tile k (+LQ @k=0)
      } else {
        asm volatile("s_waitcnt vmcnt(0)" ::: "memory");
      }
      SBAR();
      const u16* TAc = sh + 32768 + (k & 1) * 16384;
      const u16* TBc = TAc + 8192;
#pragma unroll
      for (int ks = 0; ks < 2; ++ks) {
        short8 af[4], bg[2];
        const int k8 = ks * 32 + hi * 8;
#pragma unroll
        for (int i = 0; i < 4; ++i)
          af[i] = *(const short8*)&TAc[(wr * 64 + i * 16 + fro) * 64 + k8];
#pragma unroll
        for (int jf = 0; jf < 2; ++jf)
          bg[jf] = *(const short8*)&TBc[(wc * 32 + jf * 16 + fro) * 64 + k8];
#pragma unroll
        for (int i = 0; i < 4; ++i)
#pragma unroll
          for (int jf = 0; jf < 2; ++jf)
            acc[i][jf] = __builtin_amdgcn_mfma_f32_16x16x32_bf16(
                af[i], bg[jf], acc[i][jf], 0, 0, 0);
      }
      SBAR();
    }
    // T epilogue: scale by 1/csum[j], write LT in ab-swizzled layout
    const int col = lane & 15;
    const int r4 = hi * 4;
#pragma unroll
    for (int i = 0; i < 4; ++i)
#pragma unroll
      for (int g = 0; g < 4; ++g) {
        const int j = wr * 64 + i * 16 + r4 + g;
        const float inv = 1.f / csum[b * 128 + j];
#pragma unroll
        for (int jf = 0; jf < 2; ++jf) {
          const int d = wc * 32 + jf * 16 + col;
          LT[d * 128 + (((j >> 3) ^ (d & 7)) << 3) + (j & 7)] =
              f2bf(acc[i][jf][g] * inv);
        }
      }
  }
  __syncthreads();  // LT visible; Tstage region free for LS dbuf reuse

  // ================= phase AB =================
  const u16* Sg = Sbar + (size_t)b * 131072;
  STG32(Sg, sh + 32768);
  asm volatile("s_waitcnt vmcnt(0)" ::: "memory");
  __syncthreads();

  for (int mm = 0; mm < 8; ++mm) {
    const u16* LSc = sh + 32768 + ((size_t)(mm & 1) << 14);
    u16* LSn = sh + 32768 + ((size_t)((mm + 1) & 1) << 14);
    if (mm < 7) STG32(Sg + (size_t)(mm + 1) * 16384, LSn);

    f32x4 aa[4][2] = {};
    f32x4 ab[4][2] = {};
#pragma unroll
    for (int ks = 0; ks < 4; ++ks) {
      short8 af[4], bq[2], bt[2];
#pragma unroll
      for (int i = 0; i < 4; ++i) {
        const int r = wr * 64 + i * 16 + fro;
        af[i] = RDS(LSc, r, ks * 4 + hi);
      }
#pragma unroll
      for (int j = 0; j < 2; ++j) {
        const int r = wc * 32 + j * 16 + fro;
        bq[j] = RDS(LQ, r, ks * 4 + hi);
        bt[j] = RDS(LT, r, ks * 4 + hi);
      }
#pragma unroll
      for (int i = 0; i < 4; ++i)
#pragma unroll
        for (int j = 0; j < 2; ++j) {
          aa[i][j] =
              __builtin_amdgcn_mfma_f32_16x16x32_bf16(af[i], bq[j], aa[i][j], 0, 0, 0);
          ab[i][j] =
              __builtin_amdgcn_mfma_f32_16x16x32_bf16(af[i], bt[j], ab[i][j], 0, 0, 0);
        }
    }

    const size_t obase = (size_t)b * 2097152 + (size_t)mm * 262144 + dcol;
    __syncthreads();  // drains prefetch too
#pragma unroll
    for (int i = 0; i < 4; ++i)
#pragma unroll
      for (int j = 0; j < 2; ++j)
#pragma unroll
        for (int g = 0; g < 4; ++g)
          Ls[(wr * 64 + i * 16 + hi * 4 + g) * 128 + wc * 32 + j * 16 + fro] =
              f2bf(aa[i][j][g]);
    __syncthreads();
    short8 c8[4];
#pragma unroll
    for (int it = 0; it < 4; ++it) {
      const int row = it * 32 + srow4;
      const short8 a8 = *(const short8*)&Ls[row * 128 + sslot * 8];
      c8[it] = *(const short8*)&O[obase + (size_t)row * 2048 + sslot * 8];
      short8 p2;
#pragma unroll
      for (int k = 0; k < 8; ++k)
        p2[k] = (short)f2bf(bf2f((u16)c8[it][k]) * bf2f((u16)a8[k]));
      *(short8*)&O[obase + (size_t)row * 2048 + sslot * 8 + 512] = a8;
      *(short8*)&O[obase + (size_t)row * 2048 + sslot * 8 + 1024] = p2;
    }
    __syncthreads();
#pragma unroll
    for (int i = 0; i < 4; ++i)
#pragma unroll
      for (int j = 0; j < 2; ++j)
#pragma unroll
        for (int g = 0; g < 4; ++g)
          Ls[(wr * 64 + i * 16 + hi * 4 + g) * 128 + wc * 32 + j * 16 + fro] =
              f2bf(ab[i][j][g]);
    __syncthreads();
#pragma unroll
    for (int it = 0; it < 4; ++it) {
      const int row = it * 32 + srow4;
      const short8 b8 = *(const short8*)&Ls[row * 128 + sslot * 8];
      short8 p3;
#pragma unroll
      for (int k = 0; k < 8; ++k)
        p3[k] = (short)f2bf(bf2f((u16)c8[it][k]) * bf2f((u16)b8[k]));
      *(short8*)&O[obase + (size_t)row * 2048 + sslot * 8 + 1536] = p3;
    }
    __syncthreads();
  }
#undef STG32
#undef RDS
#undef TSTG
}

// ---- prep: C fp32 -> O chunk0 = C_t bf16 (ld 2048), Corig bf16, cbias atomic
__global__ __launch_bounds__(256) void prep_C(const float* __restrict__ C,
                                              const float* __restrict__ W0,
                                              u16* __restrict__ O,
                                              u16* __restrict__ Corig,
                                              float* __restrict__ cb) {
  __shared__ float L[64][65];
  __shared__ float P[4][64];
  const int b = blockIdx.z;
  const int d0 = blockIdx.y * 64;
  const int i0 = blockIdx.x * 64;
  const int t = threadIdx.x;
  const int cx = t & 63;
  const int rb = t >> 6;
  const float* Cb = C + ((size_t)b * 512 + d0) * 1024 + i0;
  float part = 0.f;
#pragma unroll
  for (int rr = 0; rr < 16; ++rr) {
    const int r = rb * 16 + rr;
    const float v = Cb[(size_t)r * 1024 + cx];
    L[r][cx] = v;
    part = fmaf(v, W0[d0 + r], part);
    Corig[((size_t)b * 512 + d0 + r) * 1024 + i0 + cx] = f2bf(v);
  }
  P[rb][cx] = part;
  __syncthreads();
#pragma unroll
  for (int rr = 0; rr < 16; ++rr) {
    const int il = rb * 16 + rr;
    O[((size_t)b * 1024 + i0 + il) * 2048 + d0 + cx] = f2bf(L[cx][il]);
  }
  if (rb == 0)
    atomicAdd(&cb[b * 1024 + i0 + cx], P[0][cx] + P[1][cx] + P[2][cx] + P[3][cx]);
}

// ---- prep: Q -> Qmb, Qorig, qbias atomic; also converts Wr -> Wrb ----------
__global__ __launch_bounds__(256) void prep_Q(const float* __restrict__ Q,
                                              const float* __restrict__ W0,
                                              const float* __restrict__ Wr,
                                              u16* __restrict__ Qmb,
                                              u16* __restrict__ Qorig,
                                              float* __restrict__ qb,
                                              u16* __restrict__ Wrb) {
  __shared__ float L[64][65];
  __shared__ float P[4][64];
  const int b = blockIdx.z;
  const int d0 = blockIdx.y * 64;
  const int j0 = blockIdx.x * 64;
  const int t = threadIdx.x;
  const int cx = t & 63;
  const int rb = t >> 6;
  // fused cvt_wr: flat block id in [0,1024) covers Wr (512x2048 fp32)
  {
    const int fb = (blockIdx.z * 8 + blockIdx.y) * 2 + blockIdx.x;
    const int idx = fb * 256 + t;
    const float4 v = ((const float4*)Wr)[idx];
    short4v o;
    o[0] = (short)f2bf(v.x);
    o[1] = (short)f2bf(v.y);
    o[2] = (short)f2bf(v.z);
    o[3] = (short)f2bf(v.w);
    *(short4v*)&Wrb[(size_t)idx * 4] = o;
  }
  const float* Qb = Q + ((size_t)b * 512 + d0) * 128 + j0;
  float part = 0.f;
#pragma unroll
  for (int rr = 0; rr < 16; ++rr) {
    const int r = rb * 16 + rr;
    const float v = Qb[(size_t)r * 128 + cx];
    L[r][cx] = v;
    part = fmaf(v, W0[512 + d0 + r], part);
    Qorig[((size_t)b * 512 + d0 + r) * 128 + j0 + cx] = f2bf(v);
  }
  P[rb][cx] = part;
  __syncthreads();
  const float wm = W0[1024 + d0 + cx];
#pragma unroll
  for (int rr = 0; rr < 16; ++rr) {
    const int jl = rb * 16 + rr;
    Qmb[((size_t)b * 128 + j0 + jl) * 512 + d0 + cx] = f2bf(L[cx][jl] * wm);
  }
  if (rb == 0)
    atomicAdd(&qb[b * 128 + j0 + cx], P[0][cx] + P[1][cx] + P[2][cx] + P[3][cx]);
}

extern "C" void kernel_launch(void* const* d_in, const int* in_sizes, int n_in,
                              void* d_out, int out_size, void* d_ws, size_t ws_size,
                              hipStream_t stream) {
  (void)in_sizes; (void)n_in; (void)out_size;
  const float* C = (const float*)d_in[0];
  const float* Q = (const float*)d_in[1];
  const float* cm = (const float*)d_in[2];
  const float* qm = (const float*)d_in[3];
  const float* W0 = (const float*)d_in[4];
  const float* Wr = (const float*)d_in[5];
  float* out = (float*)d_out;

  if (ws_size < 405078016ull) return;  // ~386 MiB scratch

  char* p = (char*)d_ws;
  u16* O     = (u16*)(p);                    // (B,1024,2048) bf16 [C_t|A|C*A|C*Bm]
  u16* Corig = (u16*)(p + 268435456ull);     // (B,512,1024) bf16
  u16* Qmb   = (u16*)(p + 335544320ull);     // (B,128,512)  bf16
  u16* Qorig = (u16*)(p + 343932928ull);     // (B,512,128)  bf16
  u16* EunT  = (u16*)(p + 360710144ull);     // (B,128,1024) bf16 unnorm col-exp^T
  u16* Sbar  = (u16*)(p + 377487360ull);     // (B,1024,128) bf16
  u16* Wrb   = (u16*)(p + 402653184ull);     // (512,2048)   bf16
  float* cb  = (float*)(p + 404750336ull);   // (B,1024)
  float* qb  = (float*)(p + 405012480ull);   // (B,128)
  float* csum= (float*)(p + 405045248ull);   // (B,128)

  (void)hipFuncSetAttribute((const void*)gemm8b,
                            hipFuncAttributeMaxDynamicSharedMemorySize, 163840);
  (void)hipFuncSetAttribute((const void*)gemm_tab,
                            hipFuncAttributeMaxDynamicSharedMemorySize, 163840);
  (void)hipMemsetAsync(cb, 0, 327680, stream);  // cb + qb + csum contiguous

  prep_C<<<dim3(16, 8, 64), dim3(256), 0, stream>>>(C, W0, O, Corig, cb);
  prep_Q<<<dim3(2, 8, 64), dim3(256), 0, stream>>>(Q, W0, Wr, Qmb, Qorig, qb,
                                                   Wrb);

  // S-GEMM + fused row softmax + transposed unnormalized col-exp (XCD-swz)
  gemm_s<<<dim3(512), dim3(256), 0, stream>>>(O, Qmb, cb, qb, cm, qm,
                                              Sbar, EunT, csum);

  // merged T-GEMM + A/Bm GEMM (XCD-swz): chunks 1,2,3 of O
  gemm_tab<<<dim3(256), dim3(512), 163840, stream>>>(EunT, Corig, csum,
                                                     Sbar, Qorig, O);

  // R = Wr @ out^T : flat M=512, N=65536, K=2048; 16-wave 256^2
  gemm8b<<<dim3(512), dim3(1024), 163840, stream>>>(Wrb, O, out);
}

// Round 15
// 335.108 us; speedup vs baseline: 1.0091x; 1.0091x over previous
//
#include <hip/hip_runtime.h>
#include <hip/hip_bf16.h>

typedef unsigned short u16;
typedef __attribute__((ext_vector_type(8))) short short8;
typedef __attribute__((ext_vector_type(4))) short short4v;
typedef __attribute__((ext_vector_type(4))) float f32x4;

#define NEGV -1000000000000000.0f
#define SBAR() asm volatile("s_barrier" ::: "memory")

__device__ __forceinline__ u16 f2bf(float f) {
  unsigned u = __float_as_uint(f);
  unsigned r = (u + 0x7FFFu + ((u >> 16) & 1u)) >> 16;
  return (u16)r;
}
__device__ __forceinline__ float bf2f(u16 s) {
  return __uint_as_float(((unsigned)s) << 16);
}
__device__ __forceinline__ void lds16(const void* g, void* l) {
  __builtin_amdgcn_global_load_lds((const __attribute__((address_space(1))) void*)g,
                                   (__attribute__((address_space(3))) void*)l,
                                   16, 0, 0);
}

// ============ 256x256 GEMM, 16 waves (4Mx4N, 64x64/wave): out = Wrb @ O^T ===
// (r8/r13 verified, 148us — 4 barriers/K-tile; r14's 2-barrier trim was
// neutral-to-negative, reverted.) LDS 160KB: A dbuf 2x32K + B 3-buf 3x32K.
// 2 phases/K-tile; stage A(t+1)@p0, B(t+2)@p1; uniform vmcnt(2)@p1.
__global__ __launch_bounds__(1024) void gemm8b(const u16* __restrict__ A,
                                               const u16* __restrict__ B,
                                               float* __restrict__ out) {
  extern __shared__ u16 lds[];
  const int bid = blockIdx.x;
  const int wg = (bid & 7) * 64 + (bid >> 3);  // m-pair shares B-tile on one XCD
  const int m0 = (wg & 1) * 256;
  const int n0 = (wg >> 1) * 256;
  const int tid = threadIdx.x;
  const int lane = tid & 63;
  const int w = tid >> 6;   // 0..15
  const int wr = w >> 2;    // 64-row band
  const int wc = w & 3;     // 64-col band
  const int fro = lane & 15;
  const int hi = lane >> 4;
  const int kx = fro & 7;
  const int sr = lane >> 3;
  const int sgc = ((lane & 7) ^ sr) << 3;  // pre-swizzled source col (elems)

  const u16* Ag = A + (size_t)m0 * 2048;
  const u16* Bg = B + (size_t)n0 * 2048;
  const int rA = wr * 64 + fro;
  const int rB = wc * 64 + fro;

  f32x4 acc[4][4] = {};

#define STG(gp, lp) \
  lds16((gp) + (size_t)(w * 8 + sr) * 2048 + sgc, (u16*)(lp) + w * 512)
#define RDF(base, row, k16) \
  (*(const short8*)&(base)[(size_t)(row) * 64 + (((k16) ^ kx) << 3)])

  // prologue: A0, B0, B1
  STG(Ag, lds);
  STG(Ag + 262144, lds + 8192);
  STG(Bg, lds + 32768);
  STG(Bg + 262144, lds + 32768 + 8192);
  STG(Bg + 64, lds + 49152);
  STG(Bg + 262144 + 64, lds + 57344);
  asm volatile("s_waitcnt vmcnt(2)" ::: "memory");  // A0,B0 done; B1 in flight
  SBAR();

  const u16* Ac = lds;
  u16* An = lds + 16384;
  const u16* Bc = lds + 32768;   // B(t)
  const u16* Bn = lds + 49152;   // B(t+1)
  u16* Bs2 = lds + 65536;        // stage target B(t+2)

  for (int t = 0; t < 32; ++t) {
    const int kkA = (t < 31 ? t + 1 : 31) * 64;
    const int kkB = (t < 30 ? t + 2 : 31) * 64;
    short8 af[4], bf[4];

    // ---- phase 0 (ks=0): 8 ds_read; stage A(t+1); 16 MFMA
#pragma unroll
    for (int i = 0; i < 4; ++i) af[i] = RDF(Ac, rA + i * 16, hi);
#pragma unroll
    for (int j = 0; j < 4; ++j) bf[j] = RDF(Bc, rB + j * 16, hi);
    STG(Ag + kkA, An);
    STG(Ag + 262144 + kkA, An + 8192);
    SBAR();
    __builtin_amdgcn_s_setprio(1);
#pragma unroll
    for (int i = 0; i < 4; ++i)
#pragma unroll
      for (int j = 0; j < 4; ++j)
        acc[i][j] =
            __builtin_amdgcn_mfma_f32_16x16x32_bf16(af[i], bf[j], acc[i][j], 0, 0, 0);
    __builtin_amdgcn_s_setprio(0);
    SBAR();

    // ---- phase 1 (ks=1): 8 ds_read; stage B(t+2); vmcnt(2); 16 MFMA
#pragma unroll
    for (int i = 0; i < 4; ++i) af[i] = RDF(Ac, rA + i * 16, 4 + hi);
#pragma unroll
    for (int j = 0; j < 4; ++j) bf[j] = RDF(Bc, rB + j * 16, 4 + hi);
    STG(Bg + kkB, Bs2);
    STG(Bg + 262144 + kkB, Bs2 + 8192);
    asm volatile("s_waitcnt vmcnt(2)" ::: "memory");  // drain B(t+1), A(t+1)
    SBAR();
    __builtin_amdgcn_s_setprio(1);
#pragma unroll
    for (int i = 0; i < 4; ++i)
#pragma unroll
      for (int j = 0; j < 4; ++j)
        acc[i][j] =
            __builtin_amdgcn_mfma_f32_16x16x32_bf16(af[i], bf[j], acc[i][j], 0, 0, 0);
    __builtin_amdgcn_s_setprio(0);
    SBAR();

    // rotate buffers
    u16* tA = An; An = (u16*)Ac; Ac = tA;
    u16* tB = (u16*)Bc; Bc = Bn; Bn = Bs2; Bs2 = tB;
  }
  asm volatile("s_waitcnt vmcnt(0)" ::: "memory");

  // ---- epilogue: out[b][r][c], n = n0 + wc*64 + j*16 + fro
  const int crow = m0 + wr * 64 + hi * 4;
#pragma unroll
  for (int i = 0; i < 4; ++i)
#pragma unroll
    for (int j = 0; j < 4; ++j) {
      const int n = n0 + wc * 64 + j * 16 + fro;
      float* op = out + (size_t)(n >> 10) * 524288 + (n & 1023);
#pragma unroll
      for (int g = 0; g < 4; ++g)
        op[(size_t)(crow + i * 16 + g) * 1024] = acc[i][j][g];
    }
#undef STG
#undef RDF
}

// ============ S-GEMM + fused dual softmax + transposed-Eun epilogue =========
// dbuf counted-vmcnt staging; XCD-swizzled grid.
__global__ __launch_bounds__(256) void gemm_s(
    const u16* __restrict__ A, const u16* __restrict__ Bq,
    const float* __restrict__ cb, const float* __restrict__ qb,
    const float* __restrict__ cmask, const float* __restrict__ qmask,
    u16* __restrict__ Sbar, u16* __restrict__ EunT, float* __restrict__ csum) {
  __shared__ u16 As[2][128 * 64];
  __shared__ u16 Bs[2][128 * 64];
  __shared__ u16 Lt[128][136];
  __shared__ float rmaxs[2][128];
  __shared__ float rsums[2][128];
  __shared__ float cparts[2][128];
  const int bid = blockIdx.x;
  const int xcd = bid & 7;
  const int kk = bid >> 3;            // 0..63
  const int b = xcd * 8 + (kk >> 3);  // 8 m-tiles of one b share an XCD
  const int m0 = (kk & 7) * 128;
  const u16* Ab = A + (size_t)b * 2097152;
  const u16* Bb = Bq + (size_t)b * 65536;
  const int t = threadIdx.x;
  const int lane = t & 63;
  const int w = t >> 6;
  const int wr = w >> 1, wc = w & 1;
  const int srow = lane >> 3;
  const int scol = (lane & 7) * 8;

  f32x4 acc[4][4] = {};

#define SSTG(k0, sel)                                                         \
  {                                                                           \
    _Pragma("unroll") for (int qq = 0; qq < 4; ++qq) {                        \
      const int q = w * 4 + qq;                                               \
      const int r = q * 8 + srow;                                             \
      lds16(Ab + (size_t)(m0 + r) * 2048 + (k0) + scol, &As[sel][q * 512]);   \
      lds16(Bb + (size_t)r * 512 + (k0) + scol, &Bs[sel][q * 512]);           \
    }                                                                         \
  }

  SSTG(0, 0);
  for (int it = 0; it < 8; ++it) {
    if (it < 7) {
      SSTG((it + 1) * 64, (it + 1) & 1);
      asm volatile("s_waitcnt vmcnt(8)" ::: "memory");  // drain tile it only
    } else {
      asm volatile("s_waitcnt vmcnt(0)" ::: "memory");
    }
    SBAR();
    const u16* Asc = As[it & 1];
    const u16* Bsc = Bs[it & 1];
#pragma unroll
    for (int ks = 0; ks < 2; ++ks) {
      short8 af[4], bg[4];
      const int fro = lane & 15;
      const int k8 = ks * 32 + (lane >> 4) * 8;
#pragma unroll
      for (int i = 0; i < 4; ++i)
        af[i] = *(const short8*)&Asc[(wr * 64 + i * 16 + fro) * 64 + k8];
#pragma unroll
      for (int i = 0; i < 4; ++i)
        bg[i] = *(const short8*)&Bsc[(wc * 64 + i * 16 + fro) * 64 + k8];
#pragma unroll
      for (int i = 0; i < 4; ++i)
#pragma unroll
        for (int j = 0; j < 4; ++j)
          acc[i][j] =
              __builtin_amdgcn_mfma_f32_16x16x32_bf16(af[i], bg[j], acc[i][j], 0, 0, 0);
    }
    SBAR();
  }
#undef SSTG

  const int fro = lane & 15;
  const int hi = lane >> 4;
  float qv[4], qbv[4];
#pragma unroll
  for (int j = 0; j < 4; ++j) {
    const int cc = wc * 64 + j * 16 + fro;
    qv[j] = qmask[b * 128 + cc];
    qbv[j] = qb[b * 128 + cc];
  }
  float colp[4] = {0.f, 0.f, 0.f, 0.f};
#pragma unroll
  for (int i = 0; i < 4; ++i)
#pragma unroll
    for (int g = 0; g < 4; ++g) {
      const int rl = wr * 64 + i * 16 + hi * 4 + g;
      const float rb = cb[b * 1024 + m0 + rl];
      const float cv = cmask[b * 1024 + m0 + rl];
      const float coff = NEGV * (1.f - cv);
#pragma unroll
      for (int j = 0; j < 4; ++j) {
        const float v = acc[i][j][g] + rb + qbv[j];
        acc[i][j][g] = v;
        const float e = __expf(v * cv + coff);
        Lt[wc * 64 + j * 16 + fro][rl] = f2bf(e);
        colp[j] += e;
      }
    }
#pragma unroll
  for (int j = 0; j < 4; ++j) {
    colp[j] += __shfl_xor(colp[j], 16);
    colp[j] += __shfl_xor(colp[j], 32);
  }
  if (hi == 0)
#pragma unroll
    for (int j = 0; j < 4; ++j) cparts[wr][wc * 64 + j * 16 + fro] = colp[j];
  float rtmp[4][4];
#pragma unroll
  for (int i = 0; i < 4; ++i)
#pragma unroll
    for (int g = 0; g < 4; ++g) {
      float m = -3.4e38f;
#pragma unroll
      for (int j = 0; j < 4; ++j) {
        const float xm = acc[i][j][g] * qv[j] + NEGV * (1.f - qv[j]);
        acc[i][j][g] = xm;
        m = fmaxf(m, xm);
      }
#pragma unroll
      for (int o = 8; o; o >>= 1) m = fmaxf(m, __shfl_xor(m, o));
      rtmp[i][g] = m;
    }
  if (fro == 0)
#pragma unroll
    for (int i = 0; i < 4; ++i)
#pragma unroll
      for (int g = 0; g < 4; ++g)
        rmaxs[wc][wr * 64 + i * 16 + hi * 4 + g] = rtmp[i][g];
  __syncthreads();
  if (t < 128) atomicAdd(&csum[b * 128 + t], cparts[0][t] + cparts[1][t]);
  {
    const int jr = t >> 1;
    const int ih = (t & 1) * 64;
    u16* dst = EunT + (size_t)b * 131072 + (size_t)jr * 1024 + m0 + ih;
#pragma unroll
    for (int s = 0; s < 8; ++s)
      *(short8*)(dst + s * 8) = *(const short8*)&Lt[jr][ih + s * 8];
  }
#pragma unroll
  for (int i = 0; i < 4; ++i)
#pragma unroll
    for (int g = 0; g < 4; ++g) {
      const int rl = wr * 64 + i * 16 + hi * 4 + g;
      const float M = fmaxf(rmaxs[0][rl], rmaxs[1][rl]);
      float s = 0.f;
#pragma unroll
      for (int j = 0; j < 4; ++j) {
        const float p = __expf(acc[i][j][g] - M);
        acc[i][j][g] = p;
        s += p;
      }
#pragma unroll
      for (int o = 8; o; o >>= 1) s += __shfl_xor(s, o);
      rtmp[i][g] = s;
    }
  if (fro == 0)
#pragma unroll
    for (int i = 0; i < 4; ++i)
#pragma unroll
      for (int g = 0; g < 4; ++g)
        rsums[wc][wr * 64 + i * 16 + hi * 4 + g] = rtmp[i][g];
  __syncthreads();
#pragma unroll
  for (int i = 0; i < 4; ++i)
#pragma unroll
    for (int g = 0; g < 4; ++g) {
      const int rl = wr * 64 + i * 16 + hi * 4 + g;
      const float inv = 1.f / (rsums[0][rl] + rsums[1][rl]);
#pragma unroll
      for (int j = 0; j < 4; ++j)
        Sbar[((size_t)b * 1024 + m0 + rl) * 128 + wc * 64 + j * 16 + fro] =
            f2bf(acc[i][j][g] * inv);
    }
}

// ============ merged T-GEMM + A/Bm GEMM: XCD-swizzled grid, 512 thr, 160KB ==
__global__ __launch_bounds__(512) void gemm_tab(
    const u16* __restrict__ EunT, const u16* __restrict__ Corig,
    const float* __restrict__ csum, const u16* __restrict__ Sbar,
    const u16* __restrict__ Qo, u16* __restrict__ O) {
  extern __shared__ u16 sh[];
  u16* LQ = sh;             // 32KB Qo tile
  u16* LT = sh + 16384;     // 32KB T tile
  u16* Ls = sh + 65536;     // 32KB epilogue scratch
  const int bid = blockIdx.x;
  const int xcd = bid & 7;
  const int kb = bid >> 3;            // 0..31
  const int b = xcd * 8 + (kb >> 2);  // 4 dcol-blocks of one b share an XCD
  const int dcol = (kb & 3) * 128;
  const int t = threadIdx.x;
  const int lane = t & 63;
  const int w = t >> 6;
  const int wr = w >> 2, wc = w & 3;
  const int fro = lane & 15, hi = lane >> 4;
  const int srow4 = t >> 4;   // 0..31
  const int sslot = t & 15;   // 16B slot

#define STG32(gp, lp)                                                         \
  {                                                                           \
    _Pragma("unroll") for (int ii = 0; ii < 4; ++ii) {                        \
      const int row_ = ii * 32 + srow4;                                       \
      lds16((gp) + (size_t)row_ * 128 + ((sslot ^ (row_ & 7)) << 3),          \
            (u16*)(lp) + ii * 4096 + t * 8);                                  \
    }                                                                         \
  }
#define RDS(base, row, kslot)                                                 \
  (*(const short8*)&(base)[(size_t)(row) * 128 + (((kslot) ^ ((row) & 7)) << 3)])
// stage a 128x64 bf16 K-tile (linear layout [row][64]), 2 gloads/thread
#define TSTG(gp, lp)                                                          \
  {                                                                           \
    _Pragma("unroll") for (int q = 0; q < 2; ++q) {                           \
      const int row_ = q * 64 + (t >> 3);                                     \
      lds16((gp) + (size_t)row_ * 1024 + ((t & 7) << 3),                      \
            (u16*)(lp) + q * 4096 + t * 8);                                   \
    }                                                                         \
  }

  // ---- issue LQ stage early; drains at phase T's first counted vmcnt
  STG32(Qo + (size_t)b * 65536 + (size_t)dcol * 128, LQ);

  // ================= phase T (double-buffered staging) =================
  {
    const u16* Ag = EunT + (size_t)b * 131072;                       // [128j][1024i]
    const u16* Bg = Corig + (size_t)b * 524288 + (size_t)dcol * 1024;// [128d][1024i]
    f32x4 acc[4][2] = {};
    TSTG(Ag, sh + 32768);          // TA0
    TSTG(Bg, sh + 40960);          // TB0
    for (int k = 0; k < 16; ++k) {
      if (k < 15) {
        u16* nb = sh + 32768 + ((k + 1) & 1) * 16384;
        TSTG(Ag + (k + 1) * 64, nb);
        TSTG(Bg + (k + 1) * 64, nb + 8192);
        asm volatile("s_waitcnt vmcnt(4)" ::: "memory");  // drain tile k (+LQ @k=0)
      } else {
        asm volatile("s_waitcnt vmcnt(0)" ::: "memory");
      }
      SBAR();
      const u16* TAc = sh + 32768 + (k & 1) * 16384;
      const u16* TBc = TAc + 8192;
#pragma unroll
      for (int ks = 0; ks < 2; ++ks) {
        short8 af[4], bg[2];
        const int k8 = ks * 32 + hi * 8;
#pragma unroll
        for (int i = 0; i < 4; ++i)
          af[i] = *(const short8*)&TAc[(wr * 64 + i * 16 + fro) * 64 + k8];
#pragma unroll
        for (int jf = 0; jf < 2; ++jf)
          bg[jf] = *(const short8*)&TBc[(wc * 32 + jf * 16 + fro) * 64 + k8];
#pragma unroll
        for (int i = 0; i < 4; ++i)
#pragma unroll
          for (int jf = 0; jf < 2; ++jf)
            acc[i][jf] = __builtin_amdgcn_mfma_f32_16x16x32_bf16(
                af[i], bg[jf], acc[i][jf], 0, 0, 0);
      }
      SBAR();
    }
    // T epilogue: scale by 1/csum[j], write LT in ab-swizzled layout
    const int col = lane & 15;
    const int r4 = hi * 4;
#pragma unroll
    for (int i = 0; i < 4; ++i)
#pragma unroll
      for (int g = 0; g < 4; ++g) {
        const int j = wr * 64 + i * 16 + r4 + g;
        const float inv = 1.f / csum[b * 128 + j];
#pragma unroll
        for (int jf = 0; jf < 2; ++jf) {
          const int d = wc * 32 + jf * 16 + col;
          LT[d * 128 + (((j >> 3) ^ (d & 7)) << 3) + (j & 7)] =
              f2bf(acc[i][jf][g] * inv);
        }
      }
  }
  __syncthreads();  // LT visible; Tstage region free for LS dbuf reuse

  // ================= phase AB =================
  const u16* Sg = Sbar + (size_t)b * 131072;
  STG32(Sg, sh + 32768);
  asm volatile("s_waitcnt vmcnt(0)" ::: "memory");
  __syncthreads();

  for (int mm = 0; mm < 8; ++mm) {
    const u16* LSc = sh + 32768 + ((size_t)(mm & 1) << 14);
    u16* LSn = sh + 32768 + ((size_t)((mm + 1) & 1) << 14);
    if (mm < 7) STG32(Sg + (size_t)(mm + 1) * 16384, LSn);

    f32x4 aa[4][2] = {};
    f32x4 ab[4][2] = {};
#pragma unroll
    for (int ks = 0; ks < 4; ++ks) {
      short8 af[4], bq[2], bt[2];
#pragma unroll
      for (int i = 0; i < 4; ++i) {
        const int r = wr * 64 + i * 16 + fro;
        af[i] = RDS(LSc, r, ks * 4 + hi);
      }
#pragma unroll
      for (int j = 0; j < 2; ++j) {
        const int r = wc * 32 + j * 16 + fro;
        bq[j] = RDS(LQ, r, ks * 4 + hi);
        bt[j] = RDS(LT, r, ks * 4 + hi);
      }
#pragma unroll
      for (int i = 0; i < 4; ++i)
#pragma unroll
        for (int j = 0; j < 2; ++j) {
          aa[i][j] =
              __builtin_amdgcn_mfma_f32_16x16x32_bf16(af[i], bq[j], aa[i][j], 0, 0, 0);
          ab[i][j] =
              __builtin_amdgcn_mfma_f32_16x16x32_bf16(af[i], bt[j], ab[i][j], 0, 0, 0);
        }
    }

    const size_t obase = (size_t)b * 2097152 + (size_t)mm * 262144 + dcol;
    __syncthreads();  // drains prefetch too
#pragma unroll
    for (int i = 0; i < 4; ++i)
#pragma unroll
      for (int j = 0; j < 2; ++j)
#pragma unroll
        for (int g = 0; g < 4; ++g)
          Ls[(wr * 64 + i * 16 + hi * 4 + g) * 128 + wc * 32 + j * 16 + fro] =
              f2bf(aa[i][j][g]);
    __syncthreads();
    short8 c8[4];
#pragma unroll
    for (int it = 0; it < 4; ++it) {
      const int row = it * 32 + srow4;
      const short8 a8 = *(const short8*)&Ls[row * 128 + sslot * 8];
      c8[it] = *(const short8*)&O[obase + (size_t)row * 2048 + sslot * 8];
      short8 p2;
#pragma unroll
      for (int k = 0; k < 8; ++k)
        p2[k] = (short)f2bf(bf2f((u16)c8[it][k]) * bf2f((u16)a8[k]));
      *(short8*)&O[obase + (size_t)row * 2048 + sslot * 8 + 512] = a8;
      *(short8*)&O[obase + (size_t)row * 2048 + sslot * 8 + 1024] = p2;
    }
    __syncthreads();
#pragma unroll
    for (int i = 0; i < 4; ++i)
#pragma unroll
      for (int j = 0; j < 2; ++j)
#pragma unroll
        for (int g = 0; g < 4; ++g)
          Ls[(wr * 64 + i * 16 + hi * 4 + g) * 128 + wc * 32 + j * 16 + fro] =
              f2bf(ab[i][j][g]);
    __syncthreads();
#pragma unroll
    for (int it = 0; it < 4; ++it) {
      const int row = it * 32 + srow4;
      const short8 b8 = *(const short8*)&Ls[row * 128 + sslot * 8];
      short8 p3;
#pragma unroll
      for (int k = 0; k < 8; ++k)
        p3[k] = (short)f2bf(bf2f((u16)c8[it][k]) * bf2f((u16)b8[k]));
      *(short8*)&O[obase + (size_t)row * 2048 + sslot * 8 + 1536] = p3;
    }
    __syncthreads();
  }
#undef STG32
#undef RDS
#undef TSTG
}

// ---- prep: C fp32 -> O chunk0 = C_t bf16 (ld 2048), Corig bf16, cbias atomic
__global__ __launch_bounds__(256) void prep_C(const float* __restrict__ C,
                                              const float* __restrict__ W0,
                                              u16* __restrict__ O,
                                              u16* __restrict__ Corig,
                                              float* __restrict__ cb) {
  __shared__ float L[64][65];
  __shared__ float P[4][64];
  const int b = blockIdx.z;
  const int d0 = blockIdx.y * 64;
  const int i0 = blockIdx.x * 64;
  const int t = threadIdx.x;
  const int cx = t & 63;
  const int rb = t >> 6;
  const float* Cb = C + ((size_t)b * 512 + d0) * 1024 + i0;
  float part = 0.f;
#pragma unroll
  for (int rr = 0; rr < 16; ++rr) {
    const int r = rb * 16 + rr;
    const float v = Cb[(size_t)r * 1024 + cx];
    L[r][cx] = v;
    part = fmaf(v, W0[d0 + r], part);
    Corig[((size_t)b * 512 + d0 + r) * 1024 + i0 + cx] = f2bf(v);
  }
  P[rb][cx] = part;
  __syncthreads();
#pragma unroll
  for (int rr = 0; rr < 16; ++rr) {
    const int il = rb * 16 + rr;
    O[((size_t)b * 1024 + i0 + il) * 2048 + d0 + cx] = f2bf(L[cx][il]);
  }
  if (rb == 0)
    atomicAdd(&cb[b * 1024 + i0 + cx], P[0][cx] + P[1][cx] + P[2][cx] + P[3][cx]);
}

// ---- prep: Q -> Qmb, Qorig, qbias atomic; also converts Wr -> Wrb ----------
__global__ __launch_bounds__(256) void prep_Q(const float* __restrict__ Q,
                                              const float* __restrict__ W0,
                                              const float* __restrict__ Wr,
                                              u16* __restrict__ Qmb,
                                              u16* __restrict__ Qorig,
                                              float* __restrict__ qb,
                                              u16* __restrict__ Wrb) {
  __shared__ float L[64][65];
  __shared__ float P[4][64];
  const int b = blockIdx.z;
  const int d0 = blockIdx.y * 64;
  const int j0 = blockIdx.x * 64;
  const int t = threadIdx.x;
  const int cx = t & 63;
  const int rb = t >> 6;
  // fused cvt_wr: flat block id in [0,1024) covers Wr (512x2048 fp32)
  {
    const int fb = (blockIdx.z * 8 + blockIdx.y) * 2 + blockIdx.x;
    const int idx = fb * 256 + t;
    const float4 v = ((const float4*)Wr)[idx];
    short4v o;
    o[0] = (short)f2bf(v.x);
    o[1] = (short)f2bf(v.y);
    o[2] = (short)f2bf(v.z);
    o[3] = (short)f2bf(v.w);
    *(short4v*)&Wrb[(size_t)idx * 4] = o;
  }
  const float* Qb = Q + ((size_t)b * 512 + d0) * 128 + j0;
  float part = 0.f;
#pragma unroll
  for (int rr = 0; rr < 16; ++rr) {
    const int r = rb * 16 + rr;
    const float v = Qb[(size_t)r * 128 + cx];
    L[r][cx] = v;
    part = fmaf(v, W0[512 + d0 + r], part);
    Qorig[((size_t)b * 512 + d0 + r) * 128 + j0 + cx] = f2bf(v);
  }
  P[rb][cx] = part;
  __syncthreads();
  const float wm = W0[1024 + d0 + cx];
#pragma unroll
  for (int rr = 0; rr < 16; ++rr) {
    const int jl = rb * 16 + rr;
    Qmb[((size_t)b * 128 + j0 + jl) * 512 + d0 + cx] = f2bf(L[cx][jl] * wm);
  }
  if (rb == 0)
    atomicAdd(&qb[b * 128 + j0 + cx], P[0][cx] + P[1][cx] + P[2][cx] + P[3][cx]);
}

extern "C" void kernel_launch(void* const* d_in, const int* in_sizes, int n_in,
                              void* d_out, int out_size, void* d_ws, size_t ws_size,
                              hipStream_t stream) {
  (void)in_sizes; (void)n_in; (void)out_size;
  const float* C = (const float*)d_in[0];
  const float* Q = (const float*)d_in[1];
  const float* cm = (const float*)d_in[2];
  const float* qm = (const float*)d_in[3];
  const float* W0 = (const float*)d_in[4];
  const float* Wr = (const float*)d_in[5];
  float* out = (float*)d_out;

  if (ws_size < 405078016ull) return;  // ~386 MiB scratch

  char* p = (char*)d_ws;
  u16* O     = (u16*)(p);                    // (B,1024,2048) bf16 [C_t|A|C*A|C*Bm]
  u16* Corig = (u16*)(p + 268435456ull);     // (B,512,1024) bf16
  u16* Qmb   = (u16*)(p + 335544320ull);     // (B,128,512)  bf16
  u16* Qorig = (u16*)(p + 343932928ull);     // (B,512,128)  bf16
  u16* EunT  = (u16*)(p + 360710144ull);     // (B,128,1024) bf16 unnorm col-exp^T
  u16* Sbar  = (u16*)(p + 377487360ull);     // (B,1024,128) bf16
  u16* Wrb   = (u16*)(p + 402653184ull);     // (512,2048)   bf16
  float* cb  = (float*)(p + 404750336ull);   // (B,1024)
  float* qb  = (float*)(p + 405012480ull);   // (B,128)
  float* csum= (float*)(p + 405045248ull);   // (B,128)

  (void)hipFuncSetAttribute((const void*)gemm8b,
                            hipFuncAttributeMaxDynamicSharedMemorySize, 163840);
  (void)hipFuncSetAttribute((const void*)gemm_tab,
                            hipFuncAttributeMaxDynamicSharedMemorySize, 163840);
  (void)hipMemsetAsync(cb, 0, 327680, stream);  // cb + qb + csum contiguous

  prep_C<<<dim3(16, 8, 64), dim3(256), 0, stream>>>(C, W0, O, Corig, cb);
  prep_Q<<<dim3(2, 8, 64), dim3(256), 0, stream>>>(Q, W0, Wr, Qmb, Qorig, qb,
                                                   Wrb);

  // S-GEMM + fused row softmax + transposed unnormalized col-exp (XCD-swz)
  gemm_s<<<dim3(512), dim3(256), 0, stream>>>(O, Qmb, cb, qb, cm, qm,
                                              Sbar, EunT, csum);

  // merged T-GEMM + A/Bm GEMM (XCD-swz): chunks 1,2,3 of O
  gemm_tab<<<dim3(256), dim3(512), 163840, stream>>>(EunT, Corig, csum,
                                                     Sbar, Qorig, O);

  // R = Wr @ out^T : flat M=512, N=65536, K=2048; 16-wave 256^2
  gemm8b<<<dim3(512), dim3(1024), 163840, stream>>>(Wrb, O, out);
}